// Round 1
// baseline (63805.817 us; speedup 1.0000x reference)
//
#include <hip/hip_runtime.h>
#include <cstdint>
#include <cstddef>

typedef __attribute__((ext_vector_type(8))) __bf16 bhalf8;
typedef __attribute__((ext_vector_type(4))) float floatx4;

#define B_ 32
#define T_ 2048

__device__ __forceinline__ float sigm_f(float x){ return 1.0f / (1.0f + __expf(-x)); }
__device__ __forceinline__ float tanh_f(float x){ return 1.0f - 2.0f / (1.0f + __expf(2.0f*x)); }

// ---------------- init: zero barrier counters ----------------
__global__ void k_init(unsigned* bars){ if (threadIdx.x < 16u) bars[threadIdx.x] = 0u; }

// ---------------- fp32 -> bf16 convert ----------------
__global__ void k_cvt(const float* __restrict__ s, __bf16* __restrict__ d, int n){
  int i = blockIdx.x * 256 + threadIdx.x;
  if (i < n) d[i] = (__bf16)s[i];
}

// ---------------- per-b transpose: in [R][C] -> out [C][R] ----------------
template<typename TI, typename TO>
__global__ void k_transpose(const TI* __restrict__ in, TO* __restrict__ out, int R, int C){
  __shared__ float tile[32][33];
  const size_t bo = (size_t)blockIdx.z * (size_t)R * (size_t)C;
  const int c0 = blockIdx.x * 32, r0 = blockIdx.y * 32;
  const int tx = threadIdx.x, ty = threadIdx.y;
#pragma unroll
  for (int k2 = 0; k2 < 4; ++k2)
    tile[ty + k2*8][tx] = (float)in[bo + (size_t)(r0 + ty + k2*8) * C + c0 + tx];
  __syncthreads();
#pragma unroll
  for (int k2 = 0; k2 < 4; ++k2)
    out[bo + (size_t)(c0 + ty + k2*8) * R + r0 + tx] = (TO)tile[tx][ty + k2*8];
}

// ---------------- GEMM: C[M,N] = A[M,K] * W[N,K]^T + bias, all bf16 in, bf16 out ----
// A-operand frag: A[m=lane&15][k=quad*8+j]; B-operand frag: W[n=lane&15][k=quad*8+j]
// C/D frag: row(M)=quad*4+reg, col(N)=lane&15   (m89/m91-verified layouts)
__global__ __launch_bounds__(256) void k_gemm(
    const __bf16* __restrict__ A, const __bf16* __restrict__ W,
    const float* __restrict__ bias, __bf16* __restrict__ C,
    int M, int N, int K)
{
  const int tid = threadIdx.x, wave = tid >> 6, lane = tid & 63;
  const int quad = lane >> 4, l = lane & 15;
  const int wy = wave >> 1, wx = wave & 1;
  const size_t rA = (size_t)blockIdx.y * 128 + (size_t)wy * 64;
  const size_t rW = (size_t)blockIdx.x * 128 + (size_t)wx * 64;
  floatx4 acc[4][4] = {};
  for (int k0 = 0; k0 < K; k0 += 32){
    bhalf8 af[4], wf[4];
#pragma unroll
    for (int i = 0; i < 4; ++i)
      af[i] = *(const bhalf8*)(A + (rA + 16*i + l) * (size_t)K + k0 + quad*8);
#pragma unroll
    for (int j = 0; j < 4; ++j)
      wf[j] = *(const bhalf8*)(W + (rW + 16*j + l) * (size_t)K + k0 + quad*8);
#pragma unroll
    for (int i = 0; i < 4; ++i)
#pragma unroll
      for (int j = 0; j < 4; ++j)
        acc[i][j] = __builtin_amdgcn_mfma_f32_16x16x32_bf16(af[i], wf[j], acc[i][j], 0, 0, 0);
  }
#pragma unroll
  for (int j = 0; j < 4; ++j){
    const float bv = bias[rW + 16*j + l];
#pragma unroll
    for (int i = 0; i < 4; ++i)
#pragma unroll
      for (int r = 0; r < 4; ++r)
        C[(rA + 16*i + quad*4 + r) * (size_t)N + rW + 16*j + l] = (__bf16)(acc[i][j][r] + bv);
  }
}

// ---------------- grid barrier (release-only fence; no L2 invalidate) ----------------
__device__ __forceinline__ void grid_barrier(unsigned* bar, unsigned target){
  __syncthreads();                       // drains this block's vmem stores (vmcnt 0)
  if (threadIdx.x == 0){
    __builtin_amdgcn_fence(__ATOMIC_RELEASE, "agent");   // write-back L2 -> coherent point
    __hip_atomic_fetch_add(bar, 1u, __ATOMIC_RELAXED, __HIP_MEMORY_SCOPE_AGENT);
    while (__hip_atomic_load(bar, __ATOMIC_RELAXED, __HIP_MEMORY_SCOPE_AGENT) < target)
      __builtin_amdgcn_s_sleep(1);
  }
  __syncthreads();
}

// agent-coherent 16B load (bypasses possibly-stale per-XCD L2)
__device__ __forceinline__ bhalf8 load_coherent16(const __bf16* p){
  union { unsigned long long q[2]; bhalf8 v; } u;
  u.q[0] = __hip_atomic_load((const unsigned long long*)p,     __ATOMIC_RELAXED, __HIP_MEMORY_SCOPE_AGENT);
  u.q[1] = __hip_atomic_load((const unsigned long long*)p + 1, __ATOMIC_RELAXED, __HIP_MEMORY_SCOPE_AGENT);
  return u.v;
}

// ---------------- persistent GRU scan ----------------
// grid = H/16 blocks; block owns units [u0, u0+16). 4 waves = (mtile m in {0,1}) x (K-half kh).
// Weights stay in L2 (plain loads, never invalidated). h double-buffered bf16 in global,
// read via coherent loads. Block-private fp32 h in LDS for the z*h term.
template<int H>
__global__ __launch_bounds__(256) void k_scan(
    const __bf16* __restrict__ xg,   // [B*T][3H] bf16 (b_ih already added)
    const __bf16* __restrict__ whh,  // [3H][H] bf16
    const float*  __restrict__ bhh,  // [3H]
    __bf16* __restrict__ hb0, __bf16* __restrict__ hb1,  // [B][H] double buffer
    __bf16* __restrict__ Y,          // [B*T][H]
    unsigned* __restrict__ bar)
{
  __shared__ float part[2*3*2*16*17];  // [kh][gate][m][row16][col16 pad17]
  __shared__ float hown[32*17];        // private fp32 h for this block's units
  const int tid = threadIdx.x, wave = tid >> 6, lane = tid & 63;
  const int quad = lane >> 4, l = lane & 15;
  const int m = wave & 1, kh = wave >> 1;
  const int u0 = blockIdx.x * 16;
  const unsigned nblk = gridDim.x;

  for (int i = tid; i < 32*16; i += 256){
    int b = i >> 4, u = i & 15;
    hown[b*17 + u] = 0.0f;
    hb0[(size_t)b*H + u0 + u] = (__bf16)0.0f;
  }
  const float bh0 = bhh[0*H + u0 + l];
  const float bh1 = bhh[1*H + u0 + l];
  const float bh2 = bhh[2*H + u0 + l];
  const __bf16* wr0 = whh + (size_t)(0*H + u0 + l)*H + kh*(H/2);
  const __bf16* wr1 = whh + (size_t)(1*H + u0 + l)*H + kh*(H/2);
  const __bf16* wr2 = whh + (size_t)(2*H + u0 + l)*H + kh*(H/2);
  const __bf16* ar0 = hb0 + (size_t)(16*m + l)*H + kh*(H/2);
  const __bf16* ar1 = hb1 + (size_t)(16*m + l)*H + kh*(H/2);
  const int b0g = 16*m + quad*4 + 2*kh;   // gating batch-row base (C-layout rows)

  auto xgi = [&](int b, int t, int g)->size_t {
    return ((size_t)b*T_ + t)*(size_t)(3*H) + (size_t)g*H + u0 + l;
  };

  __bf16 xq[3][2];
#pragma unroll
  for (int g = 0; g < 3; ++g)
#pragma unroll
    for (int r2 = 0; r2 < 2; ++r2)
      xq[g][r2] = xg[xgi(b0g + r2, 0, g)];

  grid_barrier(bar, nblk);   // epoch 1: h0 zeros visible everywhere

  for (int t = 0; t < T_; ++t){
    const __bf16* ar = (t & 1) ? ar1 : ar0;
    __bf16* hd = (t & 1) ? hb0 : hb1;
    floatx4 a0 = {0.f,0.f,0.f,0.f}, a1 = a0, a2 = a0;
#pragma unroll
    for (int ks = 0; ks < H/64; ++ks){
      bhalf8 av = load_coherent16(ar + ks*32 + quad*8);
      bhalf8 w0 = *(const bhalf8*)(wr0 + ks*32 + quad*8);
      bhalf8 w1 = *(const bhalf8*)(wr1 + ks*32 + quad*8);
      bhalf8 w2 = *(const bhalf8*)(wr2 + ks*32 + quad*8);
      a0 = __builtin_amdgcn_mfma_f32_16x16x32_bf16(av, w0, a0, 0, 0, 0);
      a1 = __builtin_amdgcn_mfma_f32_16x16x32_bf16(av, w1, a1, 0, 0, 0);
      a2 = __builtin_amdgcn_mfma_f32_16x16x32_bf16(av, w2, a2, 0, 0, 0);
    }
    // stash partials: slot base ((kh*3+g)*2+m)*272
    const int sb = (kh*6 + m)*272;
#pragma unroll
    for (int r = 0; r < 4; ++r){
      part[sb +        (quad*4+r)*17 + l] = a0[r];
      part[sb + 544  + (quad*4+r)*17 + l] = a1[r];
      part[sb + 1088 + (quad*4+r)*17 + l] = a2[r];
    }
    __syncthreads();
    // gating: wave (m,kh) handles rows quad*4 + 2*kh + {0,1}
#pragma unroll
    for (int r2 = 0; r2 < 2; ++r2){
      const int row = quad*4 + 2*kh + r2;
      const int bb  = 16*m + row;
      const float hr = part[(0+m)*272 + row*17 + l] + part[(6+m)*272  + row*17 + l] + bh0;
      const float hz = part[(2+m)*272 + row*17 + l] + part[(8+m)*272  + row*17 + l] + bh1;
      const float hn = part[(4+m)*272 + row*17 + l] + part[(10+m)*272 + row*17 + l] + bh2;
      const float xr = (float)xq[0][r2], xz = (float)xq[1][r2], xn = (float)xq[2][r2];
      const float rg = sigm_f(xr + hr);
      const float zg = sigm_f(xz + hz);
      const float ng = tanh_f(xn + rg*hn);
      const float hp = hown[bb*17 + l];
      const float hnew = (1.0f - zg)*ng + zg*hp;
      hown[bb*17 + l] = hnew;
      hd[(size_t)bb*H + u0 + l] = (__bf16)hnew;
      Y[((size_t)bb*T_ + t)*H + u0 + l] = (__bf16)hnew;
    }
    if (t + 1 < T_){
      // prefetch next step's xg before the barrier (hides HBM latency)
#pragma unroll
      for (int g = 0; g < 3; ++g)
#pragma unroll
        for (int r2 = 0; r2 < 2; ++r2)
          xq[g][r2] = xg[xgi(b0g + r2, t + 1, g)];
      grid_barrier(bar, nblk * (unsigned)(t + 2));
    }
  }
}

// ---------------- launch ----------------
extern "C" void kernel_launch(void* const* d_in, const int* in_sizes, int n_in,
                              void* d_out, int out_size, void* d_ws, size_t ws_size,
                              hipStream_t stream) {
  (void)in_sizes; (void)n_in; (void)out_size; (void)ws_size;
  const float* x = (const float*)d_in[0];
  const float* wih[4] = {(const float*)d_in[1], (const float*)d_in[5], (const float*)d_in[9],  (const float*)d_in[13]};
  const float* whh[4] = {(const float*)d_in[2], (const float*)d_in[6], (const float*)d_in[10], (const float*)d_in[14]};
  const float* bih[4] = {(const float*)d_in[3], (const float*)d_in[7], (const float*)d_in[11], (const float*)d_in[15]};
  const float* bhh[4] = {(const float*)d_in[4], (const float*)d_in[8], (const float*)d_in[12], (const float*)d_in[16]};
  float* out = (float*)d_out;

  char* ws = (char*)d_ws;
  size_t off = 0;
  auto take = [&](size_t bytes)->char* {
    char* p = ws + off; off = (off + bytes + 255) & ~(size_t)255; return p;
  };
  const int IN[4] = {256, 512, 512, 1024};
  const int HH[4] = {512, 512, 1024, 1024};

  unsigned* bars = (unsigned*)take(64 * sizeof(unsigned));
  __bf16* wihb[4]; __bf16* whhb[4];
  for (int i = 0; i < 4; ++i){
    wihb[i] = (__bf16*)take((size_t)3*HH[i]*IN[i]*2);
    whhb[i] = (__bf16*)take((size_t)3*HH[i]*HH[i]*2);
  }
  __bf16* XG  = (__bf16*)take((size_t)B_*T_*3*1024*2);   // 402 MB
  __bf16* Ya  = (__bf16*)take((size_t)B_*T_*1024*2);     // 134 MB
  __bf16* Yb  = (__bf16*)take((size_t)B_*T_*1024*2);     // 134 MB
  __bf16* hba = (__bf16*)take((size_t)B_*1024*2);
  __bf16* hbb = (__bf16*)take((size_t)B_*1024*2);
  __bf16* X0  = Yb;  // alias: X0 dead before Yb is first written (layer-1 scan)

  k_init<<<1, 64, 0, stream>>>(bars);
  for (int i = 0; i < 4; ++i){
    const int nih = 3*HH[i]*IN[i], nhh = 3*HH[i]*HH[i];
    k_cvt<<<(nih + 255)/256, 256, 0, stream>>>(wih[i], wihb[i], nih);
    k_cvt<<<(nhh + 255)/256, 256, 0, stream>>>(whh[i], whhb[i], nhh);
  }
  // x [B][256][T] -> X0 [B][T][256] bf16
  k_transpose<float, __bf16><<<dim3(T_/32, 256/32, B_), dim3(32, 8), 0, stream>>>(x, X0, 256, T_);

  const int M = B_ * T_;
  // layer 00: 256 -> 512
  k_gemm<<<dim3(1536/128, M/128), 256, 0, stream>>>(X0, wihb[0], bih[0], XG, M, 1536, 256);
  k_scan<512><<<32, 256, 0, stream>>>(XG, whhb[0], bhh[0], hba, hbb, Ya, bars + 0);
  // layer 01: 512 -> 512
  k_gemm<<<dim3(1536/128, M/128), 256, 0, stream>>>(Ya, wihb[1], bih[1], XG, M, 1536, 512);
  k_scan<512><<<32, 256, 0, stream>>>(XG, whhb[1], bhh[1], hba, hbb, Yb, bars + 4);
  // layer 10: 512 -> 1024
  k_gemm<<<dim3(3072/128, M/128), 256, 0, stream>>>(Yb, wihb[2], bih[2], XG, M, 3072, 512);
  k_scan<1024><<<64, 256, 0, stream>>>(XG, whhb[2], bhh[2], hba, hbb, Ya, bars + 8);
  // layer 11: 1024 -> 1024
  k_gemm<<<dim3(3072/128, M/128), 256, 0, stream>>>(Ya, wihb[3], bih[3], XG, M, 3072, 1024);
  k_scan<1024><<<64, 256, 0, stream>>>(XG, whhb[3], bhh[3], hba, hbb, Yb, bars + 12);
  // Yb [B][T][1024] -> out [B][1024][T] fp32
  k_transpose<__bf16, float><<<dim3(1024/32, T_/32, B_), dim3(32, 8), 0, stream>>>(Yb, out, T_, 1024);
}